// Round 2
// baseline (25039.732 us; speedup 1.0000x reference)
//
#include <hip/hip_runtime.h>
#include <hip/hip_bf16.h>

// Particle-filter VAE ELBO, MI355X single-fused-kernel implementation.
// Round 2: output dtype fixed to float32 (reference returns f32; round-1 bf16
// write was the 422-absmax failure). RNG = JAX threefry2x32, partitionable.

#define WS_KG    0        // [2][16][128]  (set 0 = t0, set 1 = t>=1)
#define WS_OMA   4096     // [2][16][16]
#define WS_L     4608     // [2][16][16]
#define WS_RSTDZ 5120     // [2][16]
#define WS_RSTDX 5152     // [128]
#define WS_CONST 5280     // [0]=c_obs, [1]=cc(set0)=c_pz0-c_qz0, [2]=cc(set1)

#define LOG2PI_F 1.8378770664093453f

__device__ __forceinline__ unsigned rotl32(unsigned v, int r) {
  return (v << r) | (v >> (32 - r));
}

// Threefry-2x32, 20 rounds, exactly JAX's schedule.
__device__ __forceinline__ void tf2x32(unsigned k0, unsigned k1,
                                       unsigned c0, unsigned c1,
                                       unsigned& o0, unsigned& o1) {
  unsigned ks2 = k0 ^ k1 ^ 0x1BD11BDAu;
  unsigned x0 = c0 + k0, x1 = c1 + k1;
#define TF_R4(ra, rb, rc, rd) \
  x0 += x1; x1 = rotl32(x1, ra); x1 ^= x0; \
  x0 += x1; x1 = rotl32(x1, rb); x1 ^= x0; \
  x0 += x1; x1 = rotl32(x1, rc); x1 ^= x0; \
  x0 += x1; x1 = rotl32(x1, rd); x1 ^= x0;
  TF_R4(13, 15, 26, 6)  x0 += k1;  x1 += ks2 + 1u;
  TF_R4(17, 29, 16, 24) x0 += ks2; x1 += k0 + 2u;
  TF_R4(13, 15, 26, 6)  x0 += k0;  x1 += k1 + 3u;
  TF_R4(17, 29, 16, 24) x0 += k1;  x1 += ks2 + 4u;
  TF_R4(13, 15, 26, 6)  x0 += ks2; x1 += k0 + 5u;
#undef TF_R4
  o0 = x0; o1 = x1;
}

// XLA ErfInv32 polynomial (Giles), matches jax.lax.erf_inv f32 lowering.
__device__ __forceinline__ float erfinv_f(float x) {
  float w = -log1pf(-x * x);
  float p;
  if (w < 5.0f) {
    w -= 2.5f;
    p = 2.81022636e-08f;
    p = fmaf(p, w, 3.43273939e-07f);
    p = fmaf(p, w, -3.5233877e-06f);
    p = fmaf(p, w, -4.39150654e-06f);
    p = fmaf(p, w, 0.00021858087f);
    p = fmaf(p, w, -0.00125372503f);
    p = fmaf(p, w, -0.00417768164f);
    p = fmaf(p, w, 0.246640727f);
    p = fmaf(p, w, 1.50140941f);
  } else {
    w = sqrtf(w) - 3.0f;
    p = -0.000200214257f;
    p = fmaf(p, w, 0.000100950558f);
    p = fmaf(p, w, 0.00134934322f);
    p = fmaf(p, w, -0.00367342844f);
    p = fmaf(p, w, 0.00573950773f);
    p = fmaf(p, w, -0.0076224613f);
    p = fmaf(p, w, 0.00943887047f);
    p = fmaf(p, w, 1.00167406f);
    p = fmaf(p, w, 2.83297682f);
  }
  return p * x;
}

// jax.random.normal bit path: uniform in [nextafter(-1,0), 1), sqrt2*erfinv.
__device__ __forceinline__ float normal_from_bits(unsigned bits) {
  float f = __uint_as_float((bits >> 9) | 0x3f800000u) - 1.0f;  // [0,1)
  const float lo = -0.99999994f;
  float uu = fmaxf(lo, fmaf(f, 2.0f, lo));  // (hi-lo) rounds to exactly 2.0f
  return 1.41421354f * erfinv_f(uu);
}

__device__ __forceinline__ float tanh_fast(float x) {
  float e = __expf(2.0f * x);  // overflow -> inf -> result 1; underflow -> -1
  return 1.0f - 2.0f * __builtin_amdgcn_rcpf(e + 1.0f);
}

// ---------------- precompute kernel: Kalman quantities into ws --------------
__global__ void precomp_kernel(const float* __restrict__ Rz,
                               const float* __restrict__ Rz0,
                               const float* __restrict__ Rx,
                               const float* __restrict__ Bobs,
                               float* __restrict__ ws) {
  __shared__ float svarx[128];
  __shared__ float svarz[16];
  __shared__ float sprec[16][16];
  __shared__ float saug[16][32];
  __shared__ float svq[16][16];
  __shared__ float sLm[16][16];
  __shared__ float skg[16][128];
  const int tid = threadIdx.x;  // 256 threads

  if (tid < 128) {
    float r = Rx[tid];
    svarx[tid] = fmaxf(r * r, 1e-8f);
    ws[WS_RSTDX + tid] = 1.0f / fmaxf(fabsf(r), 1e-4f);
  }
  if (tid == 0) {
    float a = 0.0f;
    for (int xx = 0; xx < 128; ++xx) a += logf(fmaxf(fabsf(Rx[xx]), 1e-4f));
    ws[WS_CONST + 0] = -a - 0.5f * 128.0f * LOG2PI_F;
  }
  __syncthreads();

  for (int set = 0; set < 2; ++set) {
    const float* Rzp = (set == 0) ? Rz0 : Rz;
    if (tid < 16) {
      float v = Rzp[tid] * Rzp[tid] + 1e-8f;
      svarz[tid] = v;
      ws[WS_RSTDZ + set * 16 + tid] = 1.0f / sqrtf(v);
    }
    __syncthreads();
    {  // prec = diag(1/var_z) + B diag(1/var_x) B^T
      int z1 = tid >> 4, z2 = tid & 15;
      float a = 0.0f;
      for (int xx = 0; xx < 128; ++xx)
        a += Bobs[z1 * 128 + xx] * Bobs[z2 * 128 + xx] / svarx[xx];
      if (z1 == z2) a += 1.0f / svarz[z1];
      sprec[z1][z2] = a;
    }
    __syncthreads();
    if (tid == 0) {
      // Gauss-Jordan inverse (prec is strongly diagonally dominant SPD).
      for (int r = 0; r < 16; ++r)
        for (int c2 = 0; c2 < 32; ++c2)
          saug[r][c2] = (c2 < 16) ? sprec[r][c2] : ((c2 - 16 == r) ? 1.0f : 0.0f);
      for (int p = 0; p < 16; ++p) {
        float ip = 1.0f / saug[p][p];
        for (int c2 = 0; c2 < 32; ++c2) saug[p][c2] *= ip;
        for (int r = 0; r < 16; ++r) if (r != p) {
          float f = saug[r][p];
          for (int c2 = 0; c2 < 32; ++c2) saug[r][c2] -= f * saug[p][c2];
        }
      }
      // symmetrized var_Q + 1e-8 I, then Cholesky
      for (int r = 0; r < 16; ++r)
        for (int c2 = 0; c2 < 16; ++c2)
          svq[r][c2] = 0.5f * (saug[r][16 + c2] + saug[c2][16 + r]) +
                       ((r == c2) ? 1e-8f : 0.0f);
      for (int j = 0; j < 16; ++j) {
        float d = svq[j][j];
        for (int s = 0; s < j; ++s) d -= sLm[j][s] * sLm[j][s];
        float dj = sqrtf(d);
        sLm[j][j] = dj;
        for (int r = j + 1; r < 16; ++r) {
          float a = svq[r][j];
          for (int s = 0; s < j; ++s) a -= sLm[r][s] * sLm[j][s];
          sLm[r][j] = a / dj;
        }
        for (int r = 0; r < j; ++r) sLm[r][j] = 0.0f;  // zero upper
      }
      float cc = 0.0f;  // c_pz - c_qz = sum log Ldiag - sum log std_z
      for (int j = 0; j < 16; ++j) cc += logf(sLm[j][j]) - logf(sqrtf(svarz[j]));
      ws[WS_CONST + 1 + set] = cc;
      for (int r = 0; r < 16; ++r)
        for (int c2 = 0; c2 < 16; ++c2)
          ws[WS_L + set * 256 + r * 16 + c2] = sLm[r][c2];
    }
    __syncthreads();
    // Kg = var_Q_raw @ (B / var_x)
    for (int o = tid; o < 2048; o += 256) {
      int z = o >> 7, xx = o & 127;
      float a = 0.0f;
      for (int s = 0; s < 16; ++s) a += saug[z][16 + s] * Bobs[s * 128 + xx];
      a /= svarx[xx];
      skg[z][xx] = a;
      ws[WS_KG + set * 2048 + o] = a;
    }
    __syncthreads();
    {  // oma = I - Kg @ B^T
      int z = tid >> 4, s = tid & 15;
      float a = 0.0f;
      for (int xx = 0; xx < 128; ++xx) a += skg[z][xx] * Bobs[s * 128 + xx];
      ws[WS_OMA + set * 256 + tid] = ((z == s) ? 1.0f : 0.0f) - a;
    }
    __syncthreads();
  }
}

// ---------------- main particle-filter kernel: 1 block = 1 batch -----------
#define LOADROW16(dst, base, row) do { \
  const float4* _q = (const float4*)((base) + (size_t)(row) * 16); \
  float4 _a = _q[0], _b2 = _q[1], _c2 = _q[2], _d2 = _q[3]; \
  dst[0] = _a.x;  dst[1] = _a.y;  dst[2] = _a.z;  dst[3] = _a.w; \
  dst[4] = _b2.x; dst[5] = _b2.y; dst[6] = _b2.z; dst[7] = _b2.w; \
  dst[8] = _c2.x; dst[9] = _c2.y; dst[10] = _c2.z; dst[11] = _c2.w; \
  dst[12] = _d2.x; dst[13] = _d2.y; dst[14] = _d2.z; dst[15] = _d2.w; \
} while (0)

#define TRANS_BODY(IVAL, NF_CUR, NF_NXT) do { \
  const int N_ = c + 16 * (IVAL); \
  float mf_[16]; \
  LOADROW16(mf_, mg, N_); \
  int Nn_ = N_ + 16; if (Nn_ > 511) Nn_ = c; \
  float wvN_ = sWV[N_]; \
  float p0_ = wvN_, p1_ = wvN_, p2_ = wvN_, p3_ = wvN_; \
  _Pragma("unroll") \
  for (int z = 0; z < 16; ++z) { \
    float nv_ = NF_CUR[z]; \
    p0_ = fmaf(nv_, zr[z][0], p0_); p1_ = fmaf(nv_, zr[z][1], p1_); \
    p2_ = fmaf(nv_, zr[z][2], p2_); p3_ = fmaf(nv_, zr[z][3], p3_); \
  } \
  LOADROW16(NF_NXT, ng, Nn_); \
  float t0_ = tanh_fast(p0_), t1_ = tanh_fast(p1_); \
  float t2_ = tanh_fast(p2_), t3_ = tanh_fast(p3_); \
  _Pragma("unroll") \
  for (int z = 0; z < 16; ++z) { \
    float mv_ = mf_[z]; \
    ac[z][0] = fmaf(mv_, t0_, ac[z][0]); ac[z][1] = fmaf(mv_, t1_, ac[z][1]); \
    ac[z][2] = fmaf(mv_, t2_, ac[z][2]); ac[z][3] = fmaf(mv_, t3_, ac[z][3]); \
  } \
} while (0)

__global__ __launch_bounds__(512, 1) void pf_kernel(
    const float* __restrict__ xg, const float* __restrict__ ug,
    const float* __restrict__ Bobs, const float* __restrict__ Obias,
    const float* __restrict__ mg, const float* __restrict__ ng,
    const float* __restrict__ Wug, const float* __restrict__ hg,
    const float* __restrict__ W0g, const float* __restrict__ b0g,
    const float* __restrict__ ws, float* __restrict__ out) {
  __shared__ float sQz0[16][128];   // carry Qz
  __shared__ float sQz1[16][128];   // resampled Qz
  __shared__ float sPM[16][128];    // prior mean (t>=1)
  __shared__ float sEps[16][128];
  __shared__ float sBT[128][16];    // B_obs transposed [x][z]
  __shared__ float sWV[512];        // Wu@v + h
  __shared__ float sXT[128];        // x_t - Obs_bias
  __shared__ float sRX[128];        // 1/std_x
  __shared__ float sKx[16];         // Kg @ (x_t - bias)
  __shared__ float sLW[128];
  __shared__ float sCW[128];
  __shared__ int   sIDX[128];
  __shared__ float sLLP[4][128];    // obs quad partials
  __shared__ float sLLC[4][128];    // column-phase partials

  const int tid  = threadIdx.x;
  const int b    = blockIdx.x;
  const int lane = tid & 63;
  const int wid  = tid >> 6;

  for (int o = tid; o < 2048; o += 512) {
    int z = o >> 7, xx = o & 127;
    sBT[xx][z] = Bobs[z * 128 + xx];
  }
  if (tid < 128) sRX[tid] = ws[WS_RSTDX + tid];
  __syncthreads();

  float elbo = 0.0f;

  for (int t = 0; t < 512; ++t) {
    // ============ phase A: resample(w0) | x-stage(w1) | eps(w2-6) | wv(w7) ==
    unsigned kt0, kt1;
    tf2x32(0u, 42u, 0u, (unsigned)t, kt0, kt1);        // fold_in(key(42), t)
    unsigned k2a = kt0, k2b = kt1;                      // t==0: eps key = kt
    if (t > 0) { unsigned a0, a1; tf2x32(kt0, kt1, 0u, 1u, a0, a1); k2a = a0; k2b = a1; }

    if (wid == 0 && t > 0) {
      unsigned k1a, k1b; tf2x32(kt0, kt1, 0u, 0u, k1a, k1b);  // split()[0]
      float a = sLW[2 * lane], bb = sLW[2 * lane + 1];
      float mx = fmaxf(a, bb);
      #pragma unroll
      for (int d = 32; d >= 1; d >>= 1) mx = fmaxf(mx, __shfl_xor(mx, d, 64));
      float ea = __expf(a - mx), eb = __expf(bb - mx);
      float run = ea + eb;
      #pragma unroll
      for (int d = 1; d < 64; d <<= 1) {
        float v = __shfl_up(run, (unsigned)d, 64);
        if (lane >= d) run += v;
      }
      float tot = __shfl(run, 63, 64);
      float inv = 1.0f / tot;
      sCW[2 * lane]     = (run - eb) * inv;
      sCW[2 * lane + 1] = run * inv;
      unsigned o0, o1;
      tf2x32(k1a, k1b, 0u, (unsigned)b, o0, o1);
      unsigned bits = o0 ^ o1;
      float u0 = __uint_as_float((bits >> 9) | 0x3f800000u) - 1.0f;  // U[0,1)
      #pragma unroll
      for (int half = 0; half < 2; ++half) {
        int j = 2 * lane + half;
        float p = (u0 + (float)j) * 0.0078125f;
        int lo = 0, hi = 128;
        #pragma unroll
        for (int itr = 0; itr < 7; ++itr) {
          int mid = (lo + hi) >> 1;
          bool cnd = sCW[mid] < p;   // bisect_left
          lo = cnd ? mid + 1 : lo;
          hi = cnd ? hi : mid;
        }
        sIDX[j] = (lo > 127) ? 127 : lo;
      }
    }
    if (wid == 1) {
      #pragma unroll
      for (int xx = lane; xx < 128; xx += 64)
        sXT[xx] = xg[((size_t)b * 128 + xx) * 512 + t] - Obias[xx];
    }
    if (wid >= 2 && wid <= 6) {
      int lt = tid - 128;  // 0..319
      for (int f = lt; f < 2048; f += 320) {
        unsigned o0, o1;
        tf2x32(k2a, k2b, 0u, (unsigned)(b * 2048 + f), o0, o1);
        sEps[f >> 7][f & 127] = normal_from_bits(o0 ^ o1);
      }
    }
    if (wid == 7 && t > 0) {
      float v[8];
      #pragma unroll
      for (int d = 0; d < 8; ++d) v[d] = ug[((size_t)b * 8 + d) * 512 + (t - 1)];
      #pragma unroll
      for (int q = 0; q < 8; ++q) {
        int N = lane + 64 * q;
        const float4* wr = (const float4*)&Wug[N * 8];
        float4 wa = wr[0], wb = wr[1];
        float a = hg[N];
        a = fmaf(wa.x, v[0], a); a = fmaf(wa.y, v[1], a);
        a = fmaf(wa.z, v[2], a); a = fmaf(wa.w, v[3], a);
        a = fmaf(wb.x, v[4], a); a = fmaf(wb.y, v[5], a);
        a = fmaf(wb.z, v[6], a); a = fmaf(wb.w, v[7], a);
        sWV[N] = a;
      }
    }
    __syncthreads();

    if (t > 0) {
      // ============ phase B: gather (w0-5) | Kx (w6) =======================
      if (wid <= 5) {
        for (int f = tid; f < 2048; f += 384) {
          int z = f >> 7, kk = f & 127;
          sQz1[z][kk] = sQz0[z][sIDX[kk]];
        }
      } else if (wid == 6) {
        int z = lane >> 2, xq = lane & 3;
        const float* Kgp = ws + WS_KG + 2048 + z * 128;
        float a = 0.0f;
        for (int jj = 0; jj < 32; ++jj) {
          int xx = xq + 4 * jj;
          a = fmaf(Kgp[xx], sXT[xx], a);
        }
        a += __shfl_xor(a, 1, 64);
        a += __shfl_xor(a, 2, 64);
        if (xq == 0) sKx[z] = a;
      }
      __syncthreads();

      // ============ phase C: transition prior mean =========================
      {
        const int c    = lane & 15;       // N-interleave chunk
        const int gg   = lane >> 4;
        const int col0 = (wid * 4 + gg) * 4;  // 4 columns per thread
        float zr[16][4];
        #pragma unroll
        for (int z = 0; z < 16; ++z) {
          float4 v = *(const float4*)&sQz1[z][col0];
          zr[z][0] = v.x; zr[z][1] = v.y; zr[z][2] = v.z; zr[z][3] = v.w;
        }
        float ac[16][4];
        #pragma unroll
        for (int z = 0; z < 16; ++z) {
          ac[z][0] = 0; ac[z][1] = 0; ac[z][2] = 0; ac[z][3] = 0;
        }
        float nfA[16], nfB[16];
        LOADROW16(nfA, ng, c);
        for (int i = 0; i < 32; i += 2) {
          TRANS_BODY(i, nfA, nfB);
          TRANS_BODY(i + 1, nfB, nfA);
        }
        // reduce over the 16 c-chunks (lanes) via butterfly
        #pragma unroll
        for (int mask = 1; mask <= 8; mask <<= 1) {
          #pragma unroll
          for (int z = 0; z < 16; ++z) {
            ac[z][0] += __shfl_xor(ac[z][0], mask, 64);
            ac[z][1] += __shfl_xor(ac[z][1], mask, 64);
            ac[z][2] += __shfl_xor(ac[z][2], mask, 64);
            ac[z][3] += __shfl_xor(ac[z][3], mask, 64);
          }
        }
        // predicated write: lane c writes row z==c (all static reg indices)
        #pragma unroll
        for (int zz = 0; zz < 16; ++zz) {
          if (c == zz) {
            float4 o;
            o.x = fmaf(0.1f, ac[zz][0], 0.9f * zr[zz][0]);
            o.y = fmaf(0.1f, ac[zz][1], 0.9f * zr[zz][1]);
            o.z = fmaf(0.1f, ac[zz][2], 0.9f * zr[zz][2]);
            o.w = fmaf(0.1f, ac[zz][3], 0.9f * zr[zz][3]);
            *(float4*)&sPM[zz][col0] = o;
          }
        }
      }
      __syncthreads();
    }

    // ============ phase D: proposal sample + ll_pz/ll_qz ====================
    {
      const int kk = tid & 127, zg = tid >> 7;
      float ep[16];
      #pragma unroll
      for (int s = 0; s < 16; ++s) ep[s] = sEps[s][kk];
      float part = 0.0f;
      if (zg == 0) {
        float q = 0.0f;
        #pragma unroll
        for (int s = 0; s < 16; ++s) q = fmaf(ep[s], ep[s], q);
        part = 0.5f * q;  // +0.5*eps^2  (the -ll_qz quad term)
      }
      const int set = (t == 0) ? 0 : 1;
      const float* Lp   = ws + WS_L + set * 256;
      const float* omap = ws + WS_OMA + set * 256;
      const float* rsz  = ws + WS_RSTDZ + set * 16;
      if (t == 0) {
        float v0[8];
        #pragma unroll
        for (int d = 0; d < 8; ++d) v0[d] = ug[((size_t)b * 8 + d) * 512];
        float pm0[16];
        #pragma unroll
        for (int s = 0; s < 16; ++s) {
          float a = b0g[s];
          #pragma unroll
          for (int d = 0; d < 8; ++d) a = fmaf(W0g[s * 8 + d], v0[d], a);
          pm0[s] = a;
        }
        const float* Kg0p = ws + WS_KG;
        #pragma unroll
        for (int zi = 0; zi < 4; ++zi) {
          int z = zg * 4 + zi;
          float mq = 0.0f;
          for (int xx = 0; xx < 128; ++xx) mq = fmaf(Kg0p[z * 128 + xx], sXT[xx], mq);
          #pragma unroll
          for (int s = 0; s < 16; ++s) mq = fmaf(omap[z * 16 + s], pm0[s], mq);
          float qn = mq;
          #pragma unroll
          for (int s = 0; s < 16; ++s) qn = fmaf(Lp[z * 16 + s], ep[s], qn);
          sQz0[z][kk] = qn;
          float pz = b0g[z];  // recompute (avoids dynamic register index)
          #pragma unroll
          for (int d = 0; d < 8; ++d) pz = fmaf(W0g[z * 8 + d], v0[d], pz);
          float r = (qn - pz) * rsz[z];
          part = fmaf(-0.5f * r, r, part);
        }
      } else {
        float pmv[16];
        #pragma unroll
        for (int s = 0; s < 16; ++s) pmv[s] = sPM[s][kk];
        #pragma unroll
        for (int zi = 0; zi < 4; ++zi) {
          int z = zg * 4 + zi;
          float mq = sKx[z];
          #pragma unroll
          for (int s = 0; s < 16; ++s) mq = fmaf(omap[z * 16 + s], pmv[s], mq);
          float qn = mq;
          #pragma unroll
          for (int s = 0; s < 16; ++s) qn = fmaf(Lp[z * 16 + s], ep[s], qn);
          sQz0[z][kk] = qn;
          float pz = sPM[z][kk];  // LDS read (avoids dynamic register index)
          float r = (qn - pz) * rsz[z];
          part = fmaf(-0.5f * r, r, part);
        }
      }
      sLLC[zg][kk] = part;
    }
    __syncthreads();

    // ============ phase E: observation ll quad ==============================
    {
      const int kk = tid & 127, xc = tid >> 7;
      float qreg[16];
      #pragma unroll
      for (int z = 0; z < 16; ++z) qreg[z] = sQz0[z][kk];
      float acc = 0.0f;
      const int x0 = xc * 32;
      #pragma unroll 4
      for (int xx = x0; xx < x0 + 32; ++xx) {
        const float4* bt = (const float4*)&sBT[xx][0];
        float4 b0v = bt[0], b1v = bt[1], b2v = bt[2], b3v = bt[3];
        float dot = 0.0f;
        dot = fmaf(b0v.x, qreg[0], dot);  dot = fmaf(b0v.y, qreg[1], dot);
        dot = fmaf(b0v.z, qreg[2], dot);  dot = fmaf(b0v.w, qreg[3], dot);
        dot = fmaf(b1v.x, qreg[4], dot);  dot = fmaf(b1v.y, qreg[5], dot);
        dot = fmaf(b1v.z, qreg[6], dot);  dot = fmaf(b1v.w, qreg[7], dot);
        dot = fmaf(b2v.x, qreg[8], dot);  dot = fmaf(b2v.y, qreg[9], dot);
        dot = fmaf(b2v.z, qreg[10], dot); dot = fmaf(b2v.w, qreg[11], dot);
        dot = fmaf(b3v.x, qreg[12], dot); dot = fmaf(b3v.y, qreg[13], dot);
        dot = fmaf(b3v.z, qreg[14], dot); dot = fmaf(b3v.w, qreg[15], dot);
        float d = (sXT[xx] - dot) * sRX[xx];
        acc = fmaf(d, d, acc);
      }
      sLLP[xc][kk] = acc;
    }
    __syncthreads();

    // ============ phase F: log weights + logsumexp ==========================
    if (wid == 0) {
      float cobs = ws[WS_CONST + 0];
      float cc = (t == 0) ? ws[WS_CONST + 1] : ws[WS_CONST + 2];
      float lw0 = 0, lw1 = 0;
      #pragma unroll
      for (int half = 0; half < 2; ++half) {
        int j = 2 * lane + half;
        float v = -0.5f * (sLLP[0][j] + sLLP[1][j] + sLLP[2][j] + sLLP[3][j]) + cobs
                + sLLC[0][j] + sLLC[1][j] + sLLC[2][j] + sLLC[3][j] + cc;
        sLW[j] = v;
        if (half) lw1 = v; else lw0 = v;
      }
      float mx = fmaxf(lw0, lw1);
      #pragma unroll
      for (int d = 32; d >= 1; d >>= 1) mx = fmaxf(mx, __shfl_xor(mx, d, 64));
      float se = __expf(lw0 - mx) + __expf(lw1 - mx);
      #pragma unroll
      for (int d = 32; d >= 1; d >>= 1) se += __shfl_xor(se, d, 64);
      elbo += logf(se) + mx - logf(128.0f);
    }
    __syncthreads();
  }

  if (tid == 0) out[b] = -elbo * (1.0f / 512.0f);
}

extern "C" void kernel_launch(void* const* d_in, const int* in_sizes, int n_in,
                              void* d_out, int out_size, void* d_ws, size_t ws_size,
                              hipStream_t stream) {
  const float* x     = (const float*)d_in[0];
  const float* u     = (const float*)d_in[1];
  const float* R_z   = (const float*)d_in[2];
  const float* R_z0  = (const float*)d_in[3];
  const float* R_x   = (const float*)d_in[4];
  const float* B_obs = (const float*)d_in[5];
  const float* Obias = (const float*)d_in[6];
  const float* m     = (const float*)d_in[7];
  const float* n     = (const float*)d_in[8];
  const float* Wu    = (const float*)d_in[9];
  const float* h     = (const float*)d_in[10];
  const float* W0    = (const float*)d_in[11];
  const float* b0    = (const float*)d_in[12];
  float* ws = (float*)d_ws;
  float* out = (float*)d_out;

  precomp_kernel<<<dim3(1), dim3(256), 0, stream>>>(R_z, R_z0, R_x, B_obs, ws);
  pf_kernel<<<dim3(128), dim3(512), 0, stream>>>(x, u, B_obs, Obias, m, n, Wu, h,
                                                 W0, b0, ws, out);
}

// Round 3
// 8827.771 us; speedup vs baseline: 2.8365x; 2.8365x over previous
//
#include <hip/hip_runtime.h>
#include <hip/hip_bf16.h>

// Particle-filter VAE ELBO, MI355X single-fused-kernel implementation.
// Round 3: bf16-MFMA transition (2 chained 16x16x32 MFMAs per wave),
// resample folded into phase F, RNG spread over all waves. Everything
// else f32. 140KB static LDS, 512 threads, 1 block/batch (128 blocks).

#define WS_KG    0        // [2][16][128]  (set 0 = t0, set 1 = t>=1)
#define WS_OMA   4096     // [2][16][16]
#define WS_L     4608     // [2][16][16]
#define WS_RSTDZ 5120     // [2][16]
#define WS_RSTDX 5152     // [128]
#define WS_CONST 5280     // [0]=c_obs, [1]=cc(set0), [2]=cc(set1)

#define LOG2PI_F 1.8378770664093453f

typedef __attribute__((ext_vector_type(8))) short short8v;
typedef __attribute__((ext_vector_type(4))) float float4v;

#define MFMA_BF16(a, b, c) __builtin_amdgcn_mfma_f32_16x16x32_bf16((a), (b), (c), 0, 0, 0)

__device__ __forceinline__ unsigned rotl32(unsigned v, int r) {
  return (v << r) | (v >> (32 - r));
}

// Threefry-2x32, 20 rounds, exactly JAX's schedule.
__device__ __forceinline__ void tf2x32(unsigned k0, unsigned k1,
                                       unsigned c0, unsigned c1,
                                       unsigned& o0, unsigned& o1) {
  unsigned ks2 = k0 ^ k1 ^ 0x1BD11BDAu;
  unsigned x0 = c0 + k0, x1 = c1 + k1;
#define TF_R4(ra, rb, rc, rd) \
  x0 += x1; x1 = rotl32(x1, ra); x1 ^= x0; \
  x0 += x1; x1 = rotl32(x1, rb); x1 ^= x0; \
  x0 += x1; x1 = rotl32(x1, rc); x1 ^= x0; \
  x0 += x1; x1 = rotl32(x1, rd); x1 ^= x0;
  TF_R4(13, 15, 26, 6)  x0 += k1;  x1 += ks2 + 1u;
  TF_R4(17, 29, 16, 24) x0 += ks2; x1 += k0 + 2u;
  TF_R4(13, 15, 26, 6)  x0 += k0;  x1 += k1 + 3u;
  TF_R4(17, 29, 16, 24) x0 += k1;  x1 += ks2 + 4u;
  TF_R4(13, 15, 26, 6)  x0 += ks2; x1 += k0 + 5u;
#undef TF_R4
  o0 = x0; o1 = x1;
}

// XLA ErfInv32 polynomial (Giles), matches jax.lax.erf_inv f32 lowering.
__device__ __forceinline__ float erfinv_f(float x) {
  float w = -log1pf(-x * x);
  float p;
  if (w < 5.0f) {
    w -= 2.5f;
    p = 2.81022636e-08f;
    p = fmaf(p, w, 3.43273939e-07f);
    p = fmaf(p, w, -3.5233877e-06f);
    p = fmaf(p, w, -4.39150654e-06f);
    p = fmaf(p, w, 0.00021858087f);
    p = fmaf(p, w, -0.00125372503f);
    p = fmaf(p, w, -0.00417768164f);
    p = fmaf(p, w, 0.246640727f);
    p = fmaf(p, w, 1.50140941f);
  } else {
    w = sqrtf(w) - 3.0f;
    p = -0.000200214257f;
    p = fmaf(p, w, 0.000100950558f);
    p = fmaf(p, w, 0.00134934322f);
    p = fmaf(p, w, -0.00367342844f);
    p = fmaf(p, w, 0.00573950773f);
    p = fmaf(p, w, -0.0076224613f);
    p = fmaf(p, w, 0.00943887047f);
    p = fmaf(p, w, 1.00167406f);
    p = fmaf(p, w, 2.83297682f);
  }
  return p * x;
}

__device__ __forceinline__ float normal_from_bits(unsigned bits) {
  float f = __uint_as_float((bits >> 9) | 0x3f800000u) - 1.0f;  // [0,1)
  const float lo = -0.99999994f;
  float uu = fmaxf(lo, fmaf(f, 2.0f, lo));
  return 1.41421354f * erfinv_f(uu);
}

__device__ __forceinline__ float tanh_fast(float x) {
  float e = __expf(2.0f * x);
  return 1.0f - 2.0f * __builtin_amdgcn_rcpf(e + 1.0f);
}

// f32 -> bf16 bits, round-to-nearest-even.
__device__ __forceinline__ short f2bf(float f) {
  unsigned u = __float_as_uint(f);
  unsigned r = (u + 0x7fffu + ((u >> 16) & 1u)) >> 16;
  return (short)r;
}

// ---------------- precompute kernel: Kalman quantities into ws --------------
__global__ void precomp_kernel(const float* __restrict__ Rz,
                               const float* __restrict__ Rz0,
                               const float* __restrict__ Rx,
                               const float* __restrict__ Bobs,
                               float* __restrict__ ws) {
  __shared__ float svarx[128];
  __shared__ float svarz[16];
  __shared__ float sprec[16][16];
  __shared__ float saug[16][32];
  __shared__ float svq[16][16];
  __shared__ float sLm[16][16];
  __shared__ float skg[16][128];
  const int tid = threadIdx.x;  // 256 threads

  if (tid < 128) {
    float r = Rx[tid];
    svarx[tid] = fmaxf(r * r, 1e-8f);
    ws[WS_RSTDX + tid] = 1.0f / fmaxf(fabsf(r), 1e-4f);
  }
  if (tid == 0) {
    float a = 0.0f;
    for (int xx = 0; xx < 128; ++xx) a += logf(fmaxf(fabsf(Rx[xx]), 1e-4f));
    ws[WS_CONST + 0] = -a - 0.5f * 128.0f * LOG2PI_F;
  }
  __syncthreads();

  for (int set = 0; set < 2; ++set) {
    const float* Rzp = (set == 0) ? Rz0 : Rz;
    if (tid < 16) {
      float v = Rzp[tid] * Rzp[tid] + 1e-8f;
      svarz[tid] = v;
      ws[WS_RSTDZ + set * 16 + tid] = 1.0f / sqrtf(v);
    }
    __syncthreads();
    {
      int z1 = tid >> 4, z2 = tid & 15;
      float a = 0.0f;
      for (int xx = 0; xx < 128; ++xx)
        a += Bobs[z1 * 128 + xx] * Bobs[z2 * 128 + xx] / svarx[xx];
      if (z1 == z2) a += 1.0f / svarz[z1];
      sprec[z1][z2] = a;
    }
    __syncthreads();
    if (tid == 0) {
      for (int r = 0; r < 16; ++r)
        for (int c2 = 0; c2 < 32; ++c2)
          saug[r][c2] = (c2 < 16) ? sprec[r][c2] : ((c2 - 16 == r) ? 1.0f : 0.0f);
      for (int p = 0; p < 16; ++p) {
        float ip = 1.0f / saug[p][p];
        for (int c2 = 0; c2 < 32; ++c2) saug[p][c2] *= ip;
        for (int r = 0; r < 16; ++r) if (r != p) {
          float f = saug[r][p];
          for (int c2 = 0; c2 < 32; ++c2) saug[r][c2] -= f * saug[p][c2];
        }
      }
      for (int r = 0; r < 16; ++r)
        for (int c2 = 0; c2 < 16; ++c2)
          svq[r][c2] = 0.5f * (saug[r][16 + c2] + saug[c2][16 + r]) +
                       ((r == c2) ? 1e-8f : 0.0f);
      for (int j = 0; j < 16; ++j) {
        float d = svq[j][j];
        for (int s = 0; s < j; ++s) d -= sLm[j][s] * sLm[j][s];
        float dj = sqrtf(d);
        sLm[j][j] = dj;
        for (int r = j + 1; r < 16; ++r) {
          float a = svq[r][j];
          for (int s = 0; s < j; ++s) a -= sLm[r][s] * sLm[j][s];
          sLm[r][j] = a / dj;
        }
        for (int r = 0; r < j; ++r) sLm[r][j] = 0.0f;
      }
      float cc = 0.0f;
      for (int j = 0; j < 16; ++j) cc += logf(sLm[j][j]) - logf(sqrtf(svarz[j]));
      ws[WS_CONST + 1 + set] = cc;
      for (int r = 0; r < 16; ++r)
        for (int c2 = 0; c2 < 16; ++c2)
          ws[WS_L + set * 256 + r * 16 + c2] = sLm[r][c2];
    }
    __syncthreads();
    for (int o = tid; o < 2048; o += 256) {
      int z = o >> 7, xx = o & 127;
      float a = 0.0f;
      for (int s = 0; s < 16; ++s) a += saug[z][16 + s] * Bobs[s * 128 + xx];
      a /= svarx[xx];
      skg[z][xx] = a;
      ws[WS_KG + set * 2048 + o] = a;
    }
    __syncthreads();
    {
      int z = tid >> 4, s = tid & 15;
      float a = 0.0f;
      for (int xx = 0; xx < 128; ++xx) a += skg[z][xx] * Bobs[s * 128 + xx];
      ws[WS_OMA + set * 256 + tid] = ((z == s) ? 1.0f : 0.0f) - a;
    }
    __syncthreads();
  }
}

// ---------------- main particle-filter kernel: 1 block = 1 batch -----------
__global__ __launch_bounds__(512, 2) void pf_kernel(
    const float* __restrict__ xg, const float* __restrict__ ug,
    const float* __restrict__ Bobs, const float* __restrict__ Obias,
    const float* __restrict__ mg, const float* __restrict__ ng,
    const float* __restrict__ Wug, const float* __restrict__ hg,
    const float* __restrict__ W0g, const float* __restrict__ b0g,
    const float* __restrict__ ws, float* __restrict__ out) {
  __shared__ float sRED[8][16][136];   // GEMM2 k-slice partials (stride 136 vs banks)
  __shared__ short sTPw[8][16][72];    // per-wave tanh(pre) transpose stage [col][row]
  __shared__ float sQz0[16][128];      // carry Qz
  __shared__ float sQz1[16][128];      // resampled Qz (f32)
  __shared__ float sPM[16][128];       // prior mean
  __shared__ float sEps[16][128];
  __shared__ short sZbT[128][24];      // resampled Qz, bf16, transposed [col][z]
  __shared__ float sBT[128][16];       // B_obs transposed
  __shared__ float sWV[512];           // Wu@v + h
  __shared__ float sXT[128];           // x_t - Obs_bias
  __shared__ float sRX[128];           // 1/std_x
  __shared__ float sKx[16];            // Kg @ (x_t - bias)
  __shared__ float sCW[128];
  __shared__ int   sIDX[128];
  __shared__ float sLLP[4][128];       // obs quad partials
  __shared__ float sLLC[4][128];       // proposal/prior partials
  __shared__ unsigned sK2b[2];         // eps key for current step

  const int tid  = threadIdx.x;
  const int b    = blockIdx.x;
  const int lane = tid & 63;
  const int wid  = tid >> 6;
  const int q    = lane >> 4;     // 0..3
  const int r16  = lane & 15;
  const int rb   = wid * 64;      // this wave's N-row base

  // ---------------- init: stage constants and weight fragments -------------
  for (int o = tid; o < 2048; o += 512) {
    int z = o >> 7, xx = o & 127;
    sBT[xx][z] = Bobs[z * 128 + xx];
  }
  if (tid < 128) sRX[tid] = ws[WS_RSTDX + tid];
  if (tid == 0) {
    unsigned kt0, kt1;
    tf2x32(0u, 42u, 0u, 0u, kt0, kt1);   // fold_in(key(42), 0): t=0 eps key
    sK2b[0] = kt0; sK2b[1] = kt1;
  }

  // A1 frags: n rows rb..rb+63, K (z) padded 16->32 with zeros.
  short8v a1[4];
#pragma unroll
  for (int rt = 0; rt < 4; ++rt) {
    short8v v = {0, 0, 0, 0, 0, 0, 0, 0};
    if (q < 2) {
      const float* p = ng + (size_t)(rb + rt * 16 + r16) * 16 + q * 8;
#pragma unroll
      for (int i = 0; i < 8; ++i) v[i] = f2bf(p[i]);
    }
    a1[rt] = v;
  }
  // A2 frags: m^T, rows z=r16, k (=N) slices rb+32*kc + 8q + i.
  short8v a2[2];
#pragma unroll
  for (int kc = 0; kc < 2; ++kc) {
    short8v v;
#pragma unroll
    for (int i = 0; i < 8; ++i)
      v[i] = f2bf(mg[(size_t)(rb + kc * 32 + q * 8 + i) * 16 + r16]);
    a2[kc] = v;
  }
  __syncthreads();

  float elbo = 0.0f;
  const float4v zero4 = {0.f, 0.f, 0.f, 0.f};

  for (int t = 0; t < 512; ++t) {
    // ===== phase A: gather(w0-5) | xT+Kx(w6) | wv(w7) ; then RNG (all) =====
    if (t > 0) {
      if (wid <= 5) {
        for (int f = tid; f < 2048; f += 384) {
          int z = f >> 7, kk = f & 127;
          float v = sQz0[z][sIDX[kk]];
          sQz1[z][kk] = v;
          sZbT[kk][z] = f2bf(v);
        }
      } else if (wid == 6) {
#pragma unroll
        for (int h2 = 0; h2 < 2; ++h2) {
          int xx = lane + 64 * h2;
          sXT[xx] = xg[((size_t)b * 128 + xx) * 512 + t] - Obias[xx];
        }
        int z = lane >> 2, xq = lane & 3;
        const float* Kgp = ws + WS_KG + 2048 + z * 128;
        float a = 0.0f;
        for (int jj = 0; jj < 32; ++jj) {
          int xx = xq + 4 * jj;
          a = fmaf(Kgp[xx], sXT[xx], a);
        }
        a += __shfl_xor(a, 1, 64);
        a += __shfl_xor(a, 2, 64);
        if (xq == 0) sKx[z] = a;
      } else {  // wid == 7
        float v[8];
#pragma unroll
        for (int d = 0; d < 8; ++d) v[d] = ug[((size_t)b * 8 + d) * 512 + (t - 1)];
#pragma unroll
        for (int qq = 0; qq < 8; ++qq) {
          int N = lane + 64 * qq;
          const float4* wr = (const float4*)&Wug[N * 8];
          float4 wa = wr[0], wb = wr[1];
          float a = hg[N];
          a = fmaf(wa.x, v[0], a); a = fmaf(wa.y, v[1], a);
          a = fmaf(wa.z, v[2], a); a = fmaf(wa.w, v[3], a);
          a = fmaf(wb.x, v[4], a); a = fmaf(wb.y, v[5], a);
          a = fmaf(wb.z, v[6], a); a = fmaf(wb.w, v[7], a);
          sWV[N] = a;
        }
      }
    } else {
      if (wid == 6) {
#pragma unroll
        for (int h2 = 0; h2 < 2; ++h2) {
          int xx = lane + 64 * h2;
          sXT[xx] = xg[((size_t)b * 128 + xx) * 512] - Obias[xx];
        }
      }
    }
    {  // RNG: 4 eps per thread, key broadcast from sK2b (set by F of t-1 / init)
      unsigned k2a = sK2b[0], k2b = sK2b[1];
#pragma unroll
      for (int j = 0; j < 4; ++j) {
        int f = tid + 512 * j;
        unsigned o0, o1;
        tf2x32(k2a, k2b, 0u, (unsigned)(b * 2048 + f), o0, o1);
        sEps[f >> 7][f & 127] = normal_from_bits(o0 ^ o1);
      }
    }
    __syncthreads();

    // ===== phase C: transition via two chained bf16 MFMAs ==================
    if (t > 0) {
      float4v cwv[4];
#pragma unroll
      for (int rt = 0; rt < 4; ++rt)
        cwv[rt] = *(const float4v*)&sWV[rb + rt * 16 + 4 * q];
      float4v acc2[8];
#pragma unroll
      for (int ct = 0; ct < 8; ++ct) acc2[ct] = zero4;

#pragma unroll
      for (int ct = 0; ct < 8; ++ct) {
        short8v bz = {0, 0, 0, 0, 0, 0, 0, 0};
        if (q < 2)
          bz = *(const short8v*)((const char*)&sZbT[0][0] +
                                 ((ct * 16 + r16) * 48 + q * 16));
        float4v d0 = MFMA_BF16(a1[0], bz, cwv[0]);
        float4v d1 = MFMA_BF16(a1[1], bz, cwv[1]);
        float4v d2 = MFMA_BF16(a1[2], bz, cwv[2]);
        float4v d3 = MFMA_BF16(a1[3], bz, cwv[3]);
#define TSTORE(RT, D) do { \
          float t0 = tanh_fast((D).x), t1 = tanh_fast((D).y); \
          float t2 = tanh_fast((D).z), t3 = tanh_fast((D).w); \
          unsigned p0 = (unsigned)(unsigned short)f2bf(t0) | \
                        ((unsigned)(unsigned short)f2bf(t1) << 16); \
          unsigned p1 = (unsigned)(unsigned short)f2bf(t2) | \
                        ((unsigned)(unsigned short)f2bf(t3) << 16); \
          *(uint2*)((char*)&sTPw[wid][r16][0] + (RT) * 32 + q * 8) = \
              make_uint2(p0, p1); \
        } while (0)
        TSTORE(0, d0); TSTORE(1, d1); TSTORE(2, d2); TSTORE(3, d3);
#undef TSTORE
        short8v b2a = *(const short8v*)((const char*)&sTPw[wid][r16][0] + q * 16);
        short8v b2b = *(const short8v*)((const char*)&sTPw[wid][r16][0] + 64 + q * 16);
        acc2[ct] = MFMA_BF16(a2[0], b2a, acc2[ct]);
        acc2[ct] = MFMA_BF16(a2[1], b2b, acc2[ct]);
      }
#pragma unroll
      for (int ct = 0; ct < 8; ++ct) {
        float* rp = &sRED[wid][4 * q][ct * 16 + r16];
        rp[0] = acc2[ct].x; rp[136] = acc2[ct].y;
        rp[272] = acc2[ct].z; rp[408] = acc2[ct].w;
      }
      __syncthreads();
      {  // reduce 8 partials + prior mean; all 512 threads, 4 elems each
        int z = tid >> 5, kk0 = (tid & 31) * 4;
        float4v s = zero4;
#pragma unroll
        for (int ww = 0; ww < 8; ++ww)
          s += *(const float4v*)&sRED[ww][z][kk0];
        float4v zq = *(const float4v*)&sQz1[z][kk0];
        float4v pm = 0.9f * zq + 0.1f * s;
        *(float4v*)&sPM[z][kk0] = pm;
      }
      __syncthreads();
    }

    // ===== phase D: proposal sample + ll_pz/ll_qz ==========================
    {
      const int kk = tid & 127, zg = tid >> 7;
      float ep[16];
#pragma unroll
      for (int s = 0; s < 16; ++s) ep[s] = sEps[s][kk];
      float part = 0.0f;
      if (zg == 0) {
        float qd = 0.0f;
#pragma unroll
        for (int s = 0; s < 16; ++s) qd = fmaf(ep[s], ep[s], qd);
        part = 0.5f * qd;
      }
      const int set = (t == 0) ? 0 : 1;
      const float* Lp   = ws + WS_L + set * 256;
      const float* omap = ws + WS_OMA + set * 256;
      const float* rsz  = ws + WS_RSTDZ + set * 16;
      if (t == 0) {
        float v0[8];
#pragma unroll
        for (int d = 0; d < 8; ++d) v0[d] = ug[((size_t)b * 8 + d) * 512];
        float pm0[16];
#pragma unroll
        for (int s = 0; s < 16; ++s) {
          float a = b0g[s];
#pragma unroll
          for (int d = 0; d < 8; ++d) a = fmaf(W0g[s * 8 + d], v0[d], a);
          pm0[s] = a;
        }
        const float* Kg0p = ws + WS_KG;
#pragma unroll
        for (int zi = 0; zi < 4; ++zi) {
          int z = zg * 4 + zi;
          float mq = 0.0f;
          for (int xx = 0; xx < 128; ++xx) mq = fmaf(Kg0p[z * 128 + xx], sXT[xx], mq);
#pragma unroll
          for (int s = 0; s < 16; ++s) mq = fmaf(omap[z * 16 + s], pm0[s], mq);
          float qn = mq;
#pragma unroll
          for (int s = 0; s < 16; ++s) qn = fmaf(Lp[z * 16 + s], ep[s], qn);
          sQz0[z][kk] = qn;
          float pz = b0g[z];
#pragma unroll
          for (int d = 0; d < 8; ++d) pz = fmaf(W0g[z * 8 + d], v0[d], pz);
          float r = (qn - pz) * rsz[z];
          part = fmaf(-0.5f * r, r, part);
        }
      } else {
        float pmv[16];
#pragma unroll
        for (int s = 0; s < 16; ++s) pmv[s] = sPM[s][kk];
#pragma unroll
        for (int zi = 0; zi < 4; ++zi) {
          int z = zg * 4 + zi;
          float mq = sKx[z];
#pragma unroll
          for (int s = 0; s < 16; ++s) mq = fmaf(omap[z * 16 + s], pmv[s], mq);
          float qn = mq;
#pragma unroll
          for (int s = 0; s < 16; ++s) qn = fmaf(Lp[z * 16 + s], ep[s], qn);
          sQz0[z][kk] = qn;
          float pz = sPM[z][kk];
          float r = (qn - pz) * rsz[z];
          part = fmaf(-0.5f * r, r, part);
        }
      }
      sLLC[zg][kk] = part;
    }
    __syncthreads();

    // ===== phase E: observation ll quad ====================================
    {
      const int kk = tid & 127, xc = tid >> 7;
      float qreg[16];
#pragma unroll
      for (int z = 0; z < 16; ++z) qreg[z] = sQz0[z][kk];
      float acc = 0.0f;
      const int x0 = xc * 32;
#pragma unroll 4
      for (int xx = x0; xx < x0 + 32; ++xx) {
        const float4* bt = (const float4*)&sBT[xx][0];
        float4 b0v = bt[0], b1v = bt[1], b2v = bt[2], b3v = bt[3];
        float dot = 0.0f;
        dot = fmaf(b0v.x, qreg[0], dot);  dot = fmaf(b0v.y, qreg[1], dot);
        dot = fmaf(b0v.z, qreg[2], dot);  dot = fmaf(b0v.w, qreg[3], dot);
        dot = fmaf(b1v.x, qreg[4], dot);  dot = fmaf(b1v.y, qreg[5], dot);
        dot = fmaf(b1v.z, qreg[6], dot);  dot = fmaf(b1v.w, qreg[7], dot);
        dot = fmaf(b2v.x, qreg[8], dot);  dot = fmaf(b2v.y, qreg[9], dot);
        dot = fmaf(b2v.z, qreg[10], dot); dot = fmaf(b2v.w, qreg[11], dot);
        dot = fmaf(b3v.x, qreg[12], dot); dot = fmaf(b3v.y, qreg[13], dot);
        dot = fmaf(b3v.z, qreg[14], dot); dot = fmaf(b3v.w, qreg[15], dot);
        float d = (sXT[xx] - dot) * sRX[xx];
        acc = fmaf(d, d, acc);
      }
      sLLP[xc][kk] = acc;
    }
    __syncthreads();

    // ===== phase F: log weights + logsumexp + resample for t+1 (w0) ========
    if (wid == 0) {
      float cobs = ws[WS_CONST + 0];
      float cc = (t == 0) ? ws[WS_CONST + 1] : ws[WS_CONST + 2];
      float lw0 = 0, lw1 = 0;
#pragma unroll
      for (int half = 0; half < 2; ++half) {
        int j = 2 * lane + half;
        float v = -0.5f * (sLLP[0][j] + sLLP[1][j] + sLLP[2][j] + sLLP[3][j]) + cobs
                + sLLC[0][j] + sLLC[1][j] + sLLC[2][j] + sLLC[3][j] + cc;
        if (half) lw1 = v; else lw0 = v;
      }
      float mx = fmaxf(lw0, lw1);
#pragma unroll
      for (int d = 32; d >= 1; d >>= 1) mx = fmaxf(mx, __shfl_xor(mx, d, 64));
      float ea = __expf(lw0 - mx), eb = __expf(lw1 - mx);
      float se = ea + eb;
#pragma unroll
      for (int d = 32; d >= 1; d >>= 1) se += __shfl_xor(se, d, 64);
      elbo += logf(se) + mx - 4.85203026f;  // log(128)

      // keys + systematic resample for step t+1
      unsigned kt0, kt1, k1a, k1b, k2a, k2b;
      tf2x32(0u, 42u, 0u, (unsigned)(t + 1), kt0, kt1);
      tf2x32(kt0, kt1, 0u, 0u, k1a, k1b);
      tf2x32(kt0, kt1, 0u, 1u, k2a, k2b);
      if (lane == 0) { sK2b[0] = k2a; sK2b[1] = k2b; }
      float run = ea + eb;
#pragma unroll
      for (int d = 1; d < 64; d <<= 1) {
        float v = __shfl_up(run, (unsigned)d, 64);
        if (lane >= d) run += v;
      }
      float tot = __shfl(run, 63, 64);
      float inv = 1.0f / tot;
      sCW[2 * lane]     = (run - eb) * inv;
      sCW[2 * lane + 1] = run * inv;
      unsigned o0, o1;
      tf2x32(k1a, k1b, 0u, (unsigned)b, o0, o1);
      unsigned bits = o0 ^ o1;
      float u0 = __uint_as_float((bits >> 9) | 0x3f800000u) - 1.0f;
#pragma unroll
      for (int half = 0; half < 2; ++half) {
        int j = 2 * lane + half;
        float p = (u0 + (float)j) * 0.0078125f;
        int lo = 0, hi = 128;
#pragma unroll
        for (int itr = 0; itr < 7; ++itr) {
          int mid = (lo + hi) >> 1;
          bool cnd = sCW[mid] < p;
          lo = cnd ? mid + 1 : lo;
          hi = cnd ? hi : mid;
        }
        sIDX[j] = (lo > 127) ? 127 : lo;
      }
    }
    __syncthreads();
  }

  if (tid == 0) out[b] = -elbo * (1.0f / 512.0f);
}

extern "C" void kernel_launch(void* const* d_in, const int* in_sizes, int n_in,
                              void* d_out, int out_size, void* d_ws, size_t ws_size,
                              hipStream_t stream) {
  const float* x     = (const float*)d_in[0];
  const float* u     = (const float*)d_in[1];
  const float* R_z   = (const float*)d_in[2];
  const float* R_z0  = (const float*)d_in[3];
  const float* R_x   = (const float*)d_in[4];
  const float* B_obs = (const float*)d_in[5];
  const float* Obias = (const float*)d_in[6];
  const float* m     = (const float*)d_in[7];
  const float* n     = (const float*)d_in[8];
  const float* Wu    = (const float*)d_in[9];
  const float* h     = (const float*)d_in[10];
  const float* W0    = (const float*)d_in[11];
  const float* b0    = (const float*)d_in[12];
  float* ws = (float*)d_ws;
  float* outp = (float*)d_out;

  precomp_kernel<<<dim3(1), dim3(256), 0, stream>>>(R_z, R_z0, R_x, B_obs, ws);
  pf_kernel<<<dim3(128), dim3(512), 0, stream>>>(x, u, B_obs, Obias, m, n, Wu, h,
                                                 W0, b0, ws, outp);
}